// Round 2
// baseline (1273.176 us; speedup 1.0000x reference)
//
#include <hip/hip_runtime.h>
#include <math.h>

// Problem constants
#define BGRAPH 64
#define NNODE  512
#define NTOT   32768        // BGRAPH*NNODE
#define CIN    128
#define HDIM   128
#define EDIM_  5
#define EDGES  524288
#define K1C    256
#define K2C    128

// ---------------------------------------------------------------------------
// BatchNorm statistics: column sums / sumsq over [NTOT, 128]
// ---------------------------------------------------------------------------
__global__ __launch_bounds__(256) void bn_stats_kernel(const float* __restrict__ x,
                                                       float* __restrict__ sum,
                                                       float* __restrict__ sumsq) {
    __shared__ float ssum[128], ssq[128];
    if (threadIdx.x < 128) { ssum[threadIdx.x] = 0.f; ssq[threadIdx.x] = 0.f; }
    __syncthreads();
    const long total = (long)NTOT * CIN;
    for (long i = (long)blockIdx.x * 256 + threadIdx.x; i < total; i += (long)gridDim.x * 256) {
        float v = x[i];
        int c = (int)(i & 127);
        atomicAdd(&ssum[c], v);
        atomicAdd(&ssq[c], v * v);
    }
    __syncthreads();
    if (threadIdx.x < 128) {
        atomicAdd(&sum[threadIdx.x], ssum[threadIdx.x]);
        atomicAdd(&sumsq[threadIdx.x], ssq[threadIdx.x]);
    }
}

__global__ __launch_bounds__(128) void bn_finalize_kernel(const float* __restrict__ sum,
                                                          const float* __restrict__ sumsq,
                                                          const float* __restrict__ gamma,
                                                          const float* __restrict__ beta,
                                                          float* __restrict__ scale,
                                                          float* __restrict__ shift) {
    int c = threadIdx.x;
    float mu  = sum[c] / (float)NTOT;
    float var = sumsq[c] / (float)NTOT - mu * mu;
    float rstd = rsqrtf(var + 1e-5f);
    float sc = gamma[c] * rstd;
    scale[c] = sc;
    shift[c] = beta[c] - mu * sc;
}

// ---------------------------------------------------------------------------
// Pack Wq|Wk|Wv|Wskip into [128,512] and biases into [512]
// ---------------------------------------------------------------------------
__global__ __launch_bounds__(256) void pack_w4_kernel(const float* __restrict__ Wq, const float* __restrict__ Wk,
                                                      const float* __restrict__ Wv, const float* __restrict__ Ws,
                                                      const float* __restrict__ bq, const float* __restrict__ bk,
                                                      const float* __restrict__ bv, const float* __restrict__ bs,
                                                      float* __restrict__ W4, float* __restrict__ bias4) {
    int i = blockIdx.x * 256 + threadIdx.x;
    if (i < 128 * 512) {
        int k = i / 512, j = i % 512;
        float v;
        if (j < 128)      v = Wq[k * 128 + j];
        else if (j < 256) v = Wk[k * 128 + (j - 128)];
        else if (j < 384) v = Wv[k * 128 + (j - 256)];
        else              v = Ws[k * 128 + (j - 384)];
        W4[i] = v;
    }
    if (i < 512) {
        float v;
        if (i < 128)      v = bq[i];
        else if (i < 256) v = bk[i - 128];
        else if (i < 384) v = bv[i - 256];
        else              v = bs[i - 384];
        bias4[i] = v;
    }
}

// ---------------------------------------------------------------------------
// CSR build: histogram, scan, scatter
// ---------------------------------------------------------------------------
__global__ __launch_bounds__(256) void hist_kernel(const int* __restrict__ ei,
                                                   int* __restrict__ deg_src,
                                                   int* __restrict__ deg_dst) {
    int e = blockIdx.x * 256 + threadIdx.x;
    if (e < EDGES) {
        atomicAdd(&deg_src[ei[e]], 1);
        atomicAdd(&deg_dst[ei[EDGES + e]], 1);
    }
}

__global__ __launch_bounds__(1024) void scan_kernel(const int* __restrict__ deg,
                                                    int* __restrict__ rowptr,
                                                    int* __restrict__ cursor) {
    __shared__ int part[1024];
    int tid = threadIdx.x;
    int base = tid * 32;
    int s = 0;
    for (int i = 0; i < 32; ++i) s += deg[base + i];
    part[tid] = s;
    __syncthreads();
    for (int off = 1; off < 1024; off <<= 1) {
        int v = part[tid];
        int add = (tid >= off) ? part[tid - off] : 0;
        __syncthreads();
        part[tid] = v + add;
        __syncthreads();
    }
    int run = (tid == 0) ? 0 : part[tid - 1];
    for (int i = 0; i < 32; ++i) {
        rowptr[base + i] = run;
        cursor[base + i] = run;
        run += deg[base + i];
    }
}

__global__ __launch_bounds__(256) void scatter_kernel(const int* __restrict__ ei,
                                                      int* __restrict__ cur_src, int* __restrict__ cur_dst,
                                                      int* __restrict__ eid_src, int* __restrict__ eid_dst) {
    int e = blockIdx.x * 256 + threadIdx.x;
    if (e < EDGES) {
        int s = ei[e], d = ei[EDGES + e];
        eid_src[atomicAdd(&cur_src[s], 1)] = e;
        eid_dst[atomicAdd(&cur_dst[d], 1)] = e;
    }
}

// ---------------------------------------------------------------------------
// Generic tiled SGEMM: C[M,Nc] = act( A @ Bw + bias + (BETA? C) )
// A: [M,K] row-major, or (TRANS_A) logical A[m,k] = Astore[k*M + m]
// Bw: [K,Nc] row-major. Batched via blockIdx.z with element strides sA/sB/sC.
// AFFINE: A element scaled per-k: a*scale[k]+shift[k] (BatchNorm fusion).
// Requires M%64==0, Nc%64==0, K%32==0.
// ---------------------------------------------------------------------------
template <bool TRANS_A, bool AFFINE, bool BETA, bool RELU>
__global__ __launch_bounds__(256) void gemm_k(const float* __restrict__ A,
                                              const float* __restrict__ Bw,
                                              const float* __restrict__ bias,
                                              float* __restrict__ C,
                                              const float* __restrict__ scale,
                                              const float* __restrict__ shift,
                                              int M, int Nc, int K,
                                              long sA, long sB, long sC) {
    const int BM = 64, BN = 64, BK = 32;
    __shared__ float As[BK][BM + 1];
    __shared__ float Bs[BK][BN + 1];
    A += (long)blockIdx.z * sA;
    Bw += (long)blockIdx.z * sB;
    C += (long)blockIdx.z * sC;
    int m0 = blockIdx.y * BM, n0 = blockIdx.x * BN;
    int tid = threadIdx.x;
    int tx = tid % 16, ty = tid / 16;
    float acc[4][4] = {};
    for (int k0 = 0; k0 < K; k0 += BK) {
        if (!TRANS_A) {
            for (int li = tid; li < BM * BK; li += 256) {
                int m = li / BK, k = li % BK;
                float a = A[(long)(m0 + m) * K + k0 + k];
                if (AFFINE) a = a * scale[k0 + k] + shift[k0 + k];
                As[k][m] = a;
            }
        } else {
            for (int li = tid; li < BM * BK; li += 256) {
                int k = li / BM, m = li % BM;
                As[k][m] = A[(long)(k0 + k) * M + m0 + m];
            }
        }
        for (int li = tid; li < BK * BN; li += 256) {
            int k = li / BN, n = li % BN;
            Bs[k][n] = Bw[(long)(k0 + k) * Nc + n0 + n];
        }
        __syncthreads();
#pragma unroll
        for (int k = 0; k < BK; ++k) {
            float a[4], b[4];
#pragma unroll
            for (int i = 0; i < 4; ++i) a[i] = As[k][ty * 4 + i];
#pragma unroll
            for (int j = 0; j < 4; ++j) b[j] = Bs[k][tx * 4 + j];
#pragma unroll
            for (int i = 0; i < 4; ++i)
#pragma unroll
                for (int j = 0; j < 4; ++j) acc[i][j] += a[i] * b[j];
        }
        __syncthreads();
    }
#pragma unroll
    for (int i = 0; i < 4; ++i) {
        int m = m0 + ty * 4 + i;
#pragma unroll
        for (int j = 0; j < 4; ++j) {
            int n = n0 + tx * 4 + j;
            float v = acc[i][j];
            if (bias) v += bias[n];
            if (BETA) v += C[(long)m * Nc + n];
            if (RELU) v = fmaxf(v, 0.f);
            C[(long)m * Nc + n] = v;
        }
    }
}

// ---------------------------------------------------------------------------
// TransformerConv attention: one wave per dst node, online softmax over its
// incoming edges. h[dst] = relu(agg + skip). qkvs layout: [node][q|k|v|skip].
// ---------------------------------------------------------------------------
__global__ __launch_bounds__(256) void attn_kernel(const float* __restrict__ qkvs,
                                                   const int* __restrict__ ei,
                                                   const float* __restrict__ eattr,
                                                   const float* __restrict__ We,
                                                   const int* __restrict__ rp_dst,
                                                   const int* __restrict__ deg_dst,
                                                   const int* __restrict__ eid_dst,
                                                   float* __restrict__ h) {
    __shared__ float sWe[EDIM_ * 128];
    for (int i = threadIdx.x; i < EDIM_ * 128; i += 256) sWe[i] = We[i];
    __syncthreads();
    int wave = threadIdx.x >> 6;
    int lane = threadIdx.x & 63;
    int node = blockIdx.x * 4 + wave;
    int f0 = lane * 2;
    const float* base = qkvs + (long)node * 512;
    float q0 = base[f0], q1 = base[f0 + 1];
    int start = rp_dst[node], cnt = deg_dst[node];
    float m = -INFINITY, l = 0.f, a0 = 0.f, a1 = 0.f;
    const float inv_sqrt_h = 0.08838834764831845f;  // 1/sqrt(128)
    for (int t = 0; t < cnt; ++t) {
        int e = eid_dst[start + t];
        int src = ei[e];
        const float* kb = qkvs + (long)src * 512 + 128;
        const float* vb = qkvs + (long)src * 512 + 256;
        float e0 = 0.f, e1 = 0.f;
#pragma unroll
        for (int d = 0; d < EDIM_; ++d) {
            float ea = eattr[e * EDIM_ + d];
            e0 += ea * sWe[d * 128 + f0];
            e1 += ea * sWe[d * 128 + f0 + 1];
        }
        float kj0 = kb[f0] + e0, kj1 = kb[f0 + 1] + e1;
        float p = q0 * kj0 + q1 * kj1;
#pragma unroll
        for (int off = 32; off; off >>= 1) p += __shfl_xor(p, off);
        float logit = p * inv_sqrt_h;
        float v0 = vb[f0] + e0, v1 = vb[f0 + 1] + e1;
        float mn = fmaxf(m, logit);
        float sc = expf(m - mn);      // first iter: exp(-inf)=0
        float w = expf(logit - mn);
        l = l * sc + w;
        a0 = a0 * sc + w * v0;
        a1 = a1 * sc + w * v1;
        m = mn;
    }
    float inv = (l > 0.f) ? 1.f / l : 0.f;
    float o0 = fmaxf(a0 * inv + base[384 + f0], 0.f);
    float o1 = fmaxf(a1 * inv + base[384 + f0 + 1], 0.f);
    h[(long)node * 128 + f0]     = o0;
    h[(long)node * 128 + f0 + 1] = o1;
}

// ---------------------------------------------------------------------------
// Row-wise softmax over NC columns, wave per row
// ---------------------------------------------------------------------------
template <int NC>
__global__ __launch_bounds__(256) void softmax_kernel(float* __restrict__ s) {
    int wave = threadIdx.x >> 6;
    int lane = threadIdx.x & 63;
    int row = blockIdx.x * 4 + wave;
    float* p = s + (long)row * NC;
    constexpr int PER = NC / 64;
    float v[PER];
    float mx = -INFINITY;
#pragma unroll
    for (int j = 0; j < PER; ++j) { v[j] = p[lane + j * 64]; mx = fmaxf(mx, v[j]); }
#pragma unroll
    for (int off = 32; off; off >>= 1) mx = fmaxf(mx, __shfl_xor(mx, off));
    float sm = 0.f;
#pragma unroll
    for (int j = 0; j < PER; ++j) { v[j] = expf(v[j] - mx); sm += v[j]; }
#pragma unroll
    for (int off = 32; off; off >>= 1) sm += __shfl_xor(sm, off);
    float inv = 1.f / sm;
#pragma unroll
    for (int j = 0; j < PER; ++j) p[lane + j * 64] = v[j] * inv;
}

// ---------------------------------------------------------------------------
// Sparse T1 = adj @ s1 via CSR-by-src: T1[n,:] = sum over out-edges s1[dst,:]
// ---------------------------------------------------------------------------
__global__ __launch_bounds__(256) void spmm_t1_kernel(const float* __restrict__ s1,
                                                      const int* __restrict__ ei_dst,  // ei + EDGES
                                                      const int* __restrict__ rp_src,
                                                      const int* __restrict__ deg_src,
                                                      const int* __restrict__ eid_src,
                                                      float* __restrict__ T1) {
    int wave = threadIdx.x >> 6;
    int lane = threadIdx.x & 63;
    int node = blockIdx.x * 4 + wave;
    int start = rp_src[node], cnt = deg_src[node];
    float acc[4] = {0.f, 0.f, 0.f, 0.f};
    for (int t = 0; t < cnt; ++t) {
        int e = eid_src[start + t];
        int dst = ei_dst[e];
        const float* sr = s1 + (long)dst * K1C;
#pragma unroll
        for (int j = 0; j < 4; ++j) acc[j] += sr[lane + j * 64];
    }
    float* out = T1 + (long)node * K1C;
#pragma unroll
    for (int j = 0; j < 4; ++j) out[lane + j * 64] = acc[j];
}

// ---------------------------------------------------------------------------
// Pooled-adj normalization: dinv[r] = 1/(sqrt(rowsum w/o diag)+eps), then
// adj[r,c] = (r==c) ? 0 : adj*dinv[r]*dinv[c]
// ---------------------------------------------------------------------------
template <int KC>
__global__ __launch_bounds__(256) void dinv_kernel(const float* __restrict__ adj,
                                                   float* __restrict__ dinv) {
    int wave = threadIdx.x >> 6;
    int lane = threadIdx.x & 63;
    int row = blockIdx.x * 4 + wave;         // in [0, BGRAPH*KC)
    int b = row / KC, r = row % KC;
    const float* p = adj + (long)b * KC * KC + (long)r * KC;
    float s = 0.f;
    for (int j = lane; j < KC; j += 64)
        if (j != r) s += p[j];
#pragma unroll
    for (int off = 32; off; off >>= 1) s += __shfl_xor(s, off);
    if (lane == 0) dinv[row] = 1.f / (sqrtf(s) + 1e-15f);
}

template <int KC>
__global__ __launch_bounds__(256) void scale_adj_kernel(float* __restrict__ adj,
                                                        const float* __restrict__ dinv) {
    long i = (long)blockIdx.x * 256 + threadIdx.x;
    int c = (int)(i % KC);
    long t = i / KC;
    int r = (int)(t % KC);
    int b = (int)(t / KC);
    float v = adj[i];
    v = (r == c) ? 0.f : v * dinv[b * KC + r] * dinv[b * KC + c];
    adj[i] = v;
}

// ---------------------------------------------------------------------------
// Readout: g = mean over K2 rows; relu(g@W_lin1+b); sigmoid(g2@W_ro+b_ro)
// ---------------------------------------------------------------------------
__global__ __launch_bounds__(128) void readout_kernel(const float* __restrict__ xd3,
                                                      const float* __restrict__ W_lin1,
                                                      const float* __restrict__ b_lin1,
                                                      const float* __restrict__ W_ro,
                                                      const float* __restrict__ b_ro,
                                                      float* __restrict__ out) {
    int b = blockIdx.x, t = threadIdx.x;
    __shared__ float g[128], g2[128], wred[2];
    const float* X = xd3 + (long)b * K2C * 128;
    float s = 0.f;
    for (int r = 0; r < K2C; ++r) s += X[r * 128 + t];
    g[t] = s * (1.f / (float)K2C);
    __syncthreads();
    float u = b_lin1[t];
    for (int k = 0; k < 128; ++k) u += g[k] * W_lin1[k * 128 + t];
    g2[t] = fmaxf(u, 0.f);
    __syncthreads();
    float p = g2[t] * W_ro[t];
#pragma unroll
    for (int off = 32; off; off >>= 1) p += __shfl_xor(p, off);
    if ((t & 63) == 0) wred[t >> 6] = p;
    __syncthreads();
    if (t == 0) {
        float tot = wred[0] + wred[1] + b_ro[0];
        out[b] = 1.f / (1.f + expf(-tot));
    }
}

// ---------------------------------------------------------------------------
extern "C" void kernel_launch(void* const* d_in, const int* in_sizes, int n_in,
                              void* d_out, int out_size, void* d_ws, size_t ws_size,
                              hipStream_t stream) {
    const float* x      = (const float*)d_in[0];
    const int*   ei     = (const int*)d_in[1];
    const float* eattr  = (const float*)d_in[2];
    // d_in[3] = batch (unused: graphs are contiguous, node/512)
    const float* gamma  = (const float*)d_in[4];
    const float* beta   = (const float*)d_in[5];
    const float* Wq     = (const float*)d_in[6];
    const float* bq     = (const float*)d_in[7];
    const float* Wk     = (const float*)d_in[8];
    const float* bk     = (const float*)d_in[9];
    const float* Wv     = (const float*)d_in[10];
    const float* bv     = (const float*)d_in[11];
    const float* We     = (const float*)d_in[12];
    const float* Wskip  = (const float*)d_in[13];
    const float* bskip  = (const float*)d_in[14];
    const float* W_mlp1 = (const float*)d_in[15];
    const float* b_mlp1 = (const float*)d_in[16];
    const float* W2_rel = (const float*)d_in[17];
    const float* b2_rel = (const float*)d_in[18];
    const float* W2_root= (const float*)d_in[19];
    const float* W_mlp2 = (const float*)d_in[20];
    const float* b_mlp2 = (const float*)d_in[21];
    const float* W3_rel = (const float*)d_in[22];
    const float* b3_rel = (const float*)d_in[23];
    const float* W3_root= (const float*)d_in[24];
    const float* W_lin1 = (const float*)d_in[25];
    const float* b_lin1 = (const float*)d_in[26];
    const float* W_ro   = (const float*)d_in[27];
    const float* b_ro   = (const float*)d_in[28];
    float* out = (float*)d_out;

    char* w = (char*)d_ws;
    const size_t MB = 1ull << 20;
    // Compact lifetime-aliased workspace plan — peak 110 MB.
    //   [0,64)   qkvs (steps 4-5) → then s1 [0,32) + T1 [32,64)
    //   [32,40)  tgc2 (step 10, T1 dead) ; [40,48) xd2 ; [48,56) s2 ; [56,64) t2
    //   [0,4)    adj2 (step 12+, s1 dead) ; [4,8) xp2 ; [8,12) t3 ; [12,16) xd3
    //   [64,80)  h ; [80,96) adj1 ; [96,104) xp1 ; [104,110) misc
    float* qkvs = (float*)(w + 0);          // [NTOT,512] 64MB
    float* s1   = (float*)(w + 0);          // [NTOT,256] 32MB
    float* T1   = (float*)(w + 32 * MB);    // [NTOT,256] 32MB
    float* tgc2 = (float*)(w + 32 * MB);    // [B,256,128] 8MB
    float* xd2  = (float*)(w + 40 * MB);    // [B,256,128] 8MB
    float* s2   = (float*)(w + 48 * MB);    // [B,256,128] 8MB
    float* t2   = (float*)(w + 56 * MB);    // [B,256,128] 8MB
    float* adj2 = (float*)(w + 0);          // [B,128,128] 4MB
    float* xp2  = (float*)(w + 4 * MB);     // [B,128,128] 4MB
    float* t3   = (float*)(w + 8 * MB);     // [B,128,128] 4MB
    float* xd3  = (float*)(w + 12 * MB);    // [B,128,128] 4MB
    float* h    = (float*)(w + 64 * MB);    // [NTOT,128] 16MB
    float* adj1 = (float*)(w + 80 * MB);    // [B,256,256] 16MB
    float* xp1  = (float*)(w + 96 * MB);    // [B,256,128] 8MB
    char* misc  = w + 104 * MB;
    float* W4     = (float*)(misc + 0x00000);   // 256KB
    float* bias4  = (float*)(misc + 0x40000);
    float* colsum = (float*)(misc + 0x41000);
    float* colsq  = (float*)(misc + 0x41200);
    float* scale  = (float*)(misc + 0x41400);
    float* shift  = (float*)(misc + 0x41600);
    float* dinv1  = (float*)(misc + 0x42000);   // 64KB
    float* dinv2  = (float*)(misc + 0x52000);   // 32KB
    int* deg_src  = (int*)(misc + 0x60000);     // 128KB each
    int* deg_dst  = (int*)(misc + 0x80000);
    int* rp_src   = (int*)(misc + 0xA0000);
    int* rp_dst   = (int*)(misc + 0xC0000);
    int* cur_src  = (int*)(misc + 0xE0000);
    int* cur_dst  = (int*)(misc + 0x100000);
    int* eid_src  = (int*)(misc + 0x120000);    // 2MB
    int* eid_dst  = (int*)(misc + 0x320000);    // 2MB

    // Zero accumulators (ws is poisoned 0xAA before every call)
    hipMemsetAsync(colsum, 0, 1024, stream);                 // colsum+colsq
    hipMemsetAsync(deg_src, 0, 2 * NTOT * sizeof(int), stream);

    // 1. BatchNorm affine params
    bn_stats_kernel<<<256, 256, 0, stream>>>(x, colsum, colsq);
    bn_finalize_kernel<<<1, 128, 0, stream>>>(colsum, colsq, gamma, beta, scale, shift);

    // 2. Pack fused qkvs weights
    pack_w4_kernel<<<256, 256, 0, stream>>>(Wq, Wk, Wv, Wskip, bq, bk, bv, bskip, W4, bias4);

    // 3. CSR by src and dst
    hist_kernel<<<EDGES / 256, 256, 0, stream>>>(ei, deg_src, deg_dst);
    scan_kernel<<<1, 1024, 0, stream>>>(deg_src, rp_src, cur_src);
    scan_kernel<<<1, 1024, 0, stream>>>(deg_dst, rp_dst, cur_dst);
    scatter_kernel<<<EDGES / 256, 256, 0, stream>>>(ei, cur_src, cur_dst, eid_src, eid_dst);

    // 4. qkvs = BN(x) @ [Wq|Wk|Wv|Wskip] + biases   (BN fused into A-load)
    gemm_k<false, true, false, false><<<dim3(512 / 64, NTOT / 64, 1), 256, 0, stream>>>(
        x, W4, bias4, qkvs, scale, shift, NTOT, 512, 128, 0, 0, 0);

    // 5. Edge-softmax attention -> h = relu(agg + skip)
    attn_kernel<<<NTOT / 4, 256, 0, stream>>>(qkvs, ei, eattr, We, rp_dst, deg_dst, eid_dst, h);

    // 6. s1 = softmax(h @ W_mlp1 + b_mlp1)   (s1 overwrites dead qkvs region)
    gemm_k<false, false, false, false><<<dim3(K1C / 64, NTOT / 64, 1), 256, 0, stream>>>(
        h, W_mlp1, b_mlp1, s1, nullptr, nullptr, NTOT, K1C, 128, 0, 0, 0);
    softmax_kernel<K1C><<<NTOT / 4, 256, 0, stream>>>(s1);

    // 7. T1 = adj @ s1 (sparse, duplicates accumulate like to_dense_adj)
    spmm_t1_kernel<<<NTOT / 4, 256, 0, stream>>>(s1, ei + EDGES, rp_src, deg_src, eid_src, T1);

    // 8. adj1 = s1^T T1 ; xp1 = s1^T h (batched per graph)
    gemm_k<true, false, false, false><<<dim3(K1C / 64, K1C / 64, BGRAPH), 256, 0, stream>>>(
        s1, T1, nullptr, adj1, nullptr, nullptr, K1C, K1C, NNODE,
        (long)NNODE * K1C, (long)NNODE * K1C, (long)K1C * K1C);
    gemm_k<true, false, false, false><<<dim3(128 / 64, K1C / 64, BGRAPH), 256, 0, stream>>>(
        s1, h, nullptr, xp1, nullptr, nullptr, K1C, 128, NNODE,
        (long)NNODE * K1C, (long)NNODE * 128, (long)K1C * 128);

    // 9. Normalize adj1 (zero diag, symmetric degree scaling)
    dinv_kernel<K1C><<<(BGRAPH * K1C) / 4, 256, 0, stream>>>(adj1, dinv1);
    scale_adj_kernel<K1C><<<(BGRAPH * K1C * K1C) / 256, 256, 0, stream>>>(adj1, dinv1);

    // 10. GraphConv2: xd2 = relu((adj1 @ xp1) @ W2_rel + b2_rel + xp1 @ W2_root)
    gemm_k<false, false, false, false><<<dim3(128 / 64, K1C / 64, BGRAPH), 256, 0, stream>>>(
        adj1, xp1, nullptr, tgc2, nullptr, nullptr, K1C, 128, K1C,
        (long)K1C * K1C, (long)K1C * 128, (long)K1C * 128);
    gemm_k<false, false, false, false><<<dim3(128 / 64, (BGRAPH * K1C) / 64, 1), 256, 0, stream>>>(
        tgc2, W2_rel, b2_rel, xd2, nullptr, nullptr, BGRAPH * K1C, 128, 128, 0, 0, 0);
    gemm_k<false, false, true, true><<<dim3(128 / 64, (BGRAPH * K1C) / 64, 1), 256, 0, stream>>>(
        xp1, W2_root, nullptr, xd2, nullptr, nullptr, BGRAPH * K1C, 128, 128, 0, 0, 0);

    // 11. s2 = softmax(xd2 @ W_mlp2 + b_mlp2)
    gemm_k<false, false, false, false><<<dim3(128 / 64, (BGRAPH * K1C) / 64, 1), 256, 0, stream>>>(
        xd2, W_mlp2, b_mlp2, s2, nullptr, nullptr, BGRAPH * K1C, K2C, 128, 0, 0, 0);
    softmax_kernel<K2C><<<(BGRAPH * K1C) / 4, 256, 0, stream>>>(s2);

    // 12. Pool2: t2 = adj1 @ s2 ; adj2 = s2^T t2 ; xp2 = s2^T xd2
    gemm_k<false, false, false, false><<<dim3(K2C / 64, K1C / 64, BGRAPH), 256, 0, stream>>>(
        adj1, s2, nullptr, t2, nullptr, nullptr, K1C, K2C, K1C,
        (long)K1C * K1C, (long)K1C * K2C, (long)K1C * K2C);
    gemm_k<true, false, false, false><<<dim3(K2C / 64, K2C / 64, BGRAPH), 256, 0, stream>>>(
        s2, t2, nullptr, adj2, nullptr, nullptr, K2C, K2C, K1C,
        (long)K1C * K2C, (long)K1C * K2C, (long)K2C * K2C);
    gemm_k<true, false, false, false><<<dim3(128 / 64, K2C / 64, BGRAPH), 256, 0, stream>>>(
        s2, xd2, nullptr, xp2, nullptr, nullptr, K2C, 128, K1C,
        (long)K1C * K2C, (long)K1C * 128, (long)K2C * 128);

    // 13. Normalize adj2
    dinv_kernel<K2C><<<(BGRAPH * K2C) / 4, 256, 0, stream>>>(adj2, dinv2);
    scale_adj_kernel<K2C><<<(BGRAPH * K2C * K2C) / 256, 256, 0, stream>>>(adj2, dinv2);

    // 14. GraphConv3 (no relu): xd3 = (adj2 @ xp2) @ W3_rel + b3_rel + xp2 @ W3_root
    gemm_k<false, false, false, false><<<dim3(128 / 64, K2C / 64, BGRAPH), 256, 0, stream>>>(
        adj2, xp2, nullptr, t3, nullptr, nullptr, K2C, 128, K2C,
        (long)K2C * K2C, (long)K2C * 128, (long)K2C * 128);
    gemm_k<false, false, false, false><<<dim3(128 / 64, (BGRAPH * K2C) / 64, 1), 256, 0, stream>>>(
        t3, W3_rel, b3_rel, xd3, nullptr, nullptr, BGRAPH * K2C, 128, 128, 0, 0, 0);
    gemm_k<false, false, true, false><<<dim3(128 / 64, (BGRAPH * K2C) / 64, 1), 256, 0, stream>>>(
        xp2, W3_root, nullptr, xd3, nullptr, nullptr, BGRAPH * K2C, 128, 128, 0, 0, 0);

    // 15. Readout -> sigmoid [B]
    readout_kernel<<<BGRAPH, 128, 0, stream>>>(xd3, W_lin1, b_lin1, W_ro, b_ro, out);

    (void)in_sizes; (void)n_in; (void)out_size; (void)ws_size;
}

// Round 3
// 751.111 us; speedup vs baseline: 1.6951x; 1.6951x over previous
//
#include <hip/hip_runtime.h>
#include <math.h>

// Problem constants
#define BGRAPH 64
#define NNODE  512
#define NTOT   32768        // BGRAPH*NNODE
#define CIN    128
#define HDIM   128
#define EDIM_  5
#define EDGES  524288
#define K1C    256
#define K2C    128

using f32x4 = __attribute__((ext_vector_type(4))) float;
using s16x8 = __attribute__((ext_vector_type(8))) short;

__device__ __forceinline__ short f2bf(float f) {
    union { float f; unsigned u; } v; v.f = f;
    unsigned r = v.u + 0x7fffu + ((v.u >> 16) & 1u);   // RNE
    return (short)(r >> 16);
}

// ---------------------------------------------------------------------------
// BatchNorm statistics: register-accumulate (stride ≡ 0 mod 128 → c fixed/thread)
// ---------------------------------------------------------------------------
__global__ __launch_bounds__(256) void bn_stats_kernel(const float* __restrict__ x,
                                                       float* __restrict__ sum,
                                                       float* __restrict__ sumsq) {
    int c = threadIdx.x & 127;
    float s = 0.f, q = 0.f;
    const long total = (long)NTOT * CIN;
    for (long i = (long)blockIdx.x * 256 + threadIdx.x; i < total; i += (long)gridDim.x * 256) {
        float v = x[i];
        s += v; q += v * v;
    }
    __shared__ float ls[256], lq[256];
    ls[threadIdx.x] = s; lq[threadIdx.x] = q;
    __syncthreads();
    if (threadIdx.x < 128) {
        atomicAdd(&sum[c], ls[threadIdx.x] + ls[threadIdx.x + 128]);
        atomicAdd(&sumsq[c], lq[threadIdx.x] + lq[threadIdx.x + 128]);
    }
}

__global__ __launch_bounds__(128) void bn_finalize_kernel(const float* __restrict__ sum,
                                                          const float* __restrict__ sumsq,
                                                          const float* __restrict__ gamma,
                                                          const float* __restrict__ beta,
                                                          float* __restrict__ scale,
                                                          float* __restrict__ shift) {
    int c = threadIdx.x;
    float mu  = sum[c] / (float)NTOT;
    float var = sumsq[c] / (float)NTOT - mu * mu;
    float rstd = rsqrtf(var + 1e-5f);
    float sc = gamma[c] * rstd;
    scale[c] = sc;
    shift[c] = beta[c] - mu * sc;
}

// ---------------------------------------------------------------------------
// Pack Wq|Wk|Wv|Wskip into [128,512] and biases into [512]
// ---------------------------------------------------------------------------
__global__ __launch_bounds__(256) void pack_w4_kernel(const float* __restrict__ Wq, const float* __restrict__ Wk,
                                                      const float* __restrict__ Wv, const float* __restrict__ Ws,
                                                      const float* __restrict__ bq, const float* __restrict__ bk,
                                                      const float* __restrict__ bv, const float* __restrict__ bs,
                                                      float* __restrict__ W4, float* __restrict__ bias4) {
    int i = blockIdx.x * 256 + threadIdx.x;
    if (i < 128 * 512) {
        int k = i / 512, j = i % 512;
        float v;
        if (j < 128)      v = Wq[k * 128 + j];
        else if (j < 256) v = Wk[k * 128 + (j - 128)];
        else if (j < 384) v = Wv[k * 128 + (j - 256)];
        else              v = Ws[k * 128 + (j - 384)];
        W4[i] = v;
    }
    if (i < 512) {
        float v;
        if (i < 128)      v = bq[i];
        else if (i < 256) v = bk[i - 128];
        else if (i < 384) v = bv[i - 256];
        else              v = bs[i - 384];
        bias4[i] = v;
    }
}

// ---------------------------------------------------------------------------
// CSR build: histogram, scan, scatter
// ---------------------------------------------------------------------------
__global__ __launch_bounds__(256) void hist_kernel(const int* __restrict__ ei,
                                                   int* __restrict__ deg_src,
                                                   int* __restrict__ deg_dst) {
    int e = blockIdx.x * 256 + threadIdx.x;
    if (e < EDGES) {
        atomicAdd(&deg_src[ei[e]], 1);
        atomicAdd(&deg_dst[ei[EDGES + e]], 1);
    }
}

__global__ __launch_bounds__(1024) void scan_kernel(const int* __restrict__ deg,
                                                    int* __restrict__ rowptr,
                                                    int* __restrict__ cursor) {
    __shared__ int part[1024];
    int tid = threadIdx.x;
    int base = tid * 32;
    int s = 0;
    for (int i = 0; i < 32; ++i) s += deg[base + i];
    part[tid] = s;
    __syncthreads();
    for (int off = 1; off < 1024; off <<= 1) {
        int v = part[tid];
        int add = (tid >= off) ? part[tid - off] : 0;
        __syncthreads();
        part[tid] = v + add;
        __syncthreads();
    }
    int run = (tid == 0) ? 0 : part[tid - 1];
    for (int i = 0; i < 32; ++i) {
        rowptr[base + i] = run;
        cursor[base + i] = run;
        run += deg[base + i];
    }
}

__global__ __launch_bounds__(256) void scatter_kernel(const int* __restrict__ ei,
                                                      int* __restrict__ cur_src, int* __restrict__ cur_dst,
                                                      int* __restrict__ eid_src, int* __restrict__ eid_dst) {
    int e = blockIdx.x * 256 + threadIdx.x;
    if (e < EDGES) {
        int s = ei[e], d = ei[EDGES + e];
        eid_src[atomicAdd(&cur_src[s], 1)] = e;
        eid_dst[atomicAdd(&cur_dst[d], 1)] = e;
    }
}

// ---------------------------------------------------------------------------
// BF16 MFMA GEMM: C[M,Nc] = act( A @ B (+ A2 @ B2) + bias )
// fp32 in global, converted to bf16 at LDS staging; fp32 accumulate (MFMA).
// !TRANS_A: A[m*lda+k].  TRANS_A: A[k*lda+m] (transpose-staged 4x4 in regs).
// B always stored [k*ldb+n] (transpose-staged).
// DUAL: for k0>=Ksplit read A2/B2 at k-Ksplit (fuses rel+root GraphConv pair).
// Tile 128x128, BK=32, 4 waves in 2x2, each wave 4x4 of 16x16x32 MFMA.
// Requires M%128==0, Nc%128==0, K%32==0.
// ---------------------------------------------------------------------------
template <bool TRANS_A, bool AFFINE, bool RELU, bool DUAL>
__global__ __launch_bounds__(256) void mgemm(const float* __restrict__ A,
                                             const float* __restrict__ B,
                                             const float* __restrict__ A2,
                                             const float* __restrict__ B2,
                                             int Ksplit,
                                             const float* __restrict__ bias,
                                             float* __restrict__ C,
                                             const float* __restrict__ scale,
                                             const float* __restrict__ shift,
                                             int M, int Nc, int K,
                                             int lda, int ldb, int ldc,
                                             long sA, long sB, long sC) {
    __shared__ __align__(16) short As[128 * 40];   // row stride 40 shorts (80 B)
    __shared__ __align__(16) short Bs[128 * 40];
    A += (long)blockIdx.z * sA;
    B += (long)blockIdx.z * sB;
    C += (long)blockIdx.z * sC;
    const int m0 = blockIdx.y * 128, n0 = blockIdx.x * 128;
    const int tid = threadIdx.x;
    const int lane16 = tid & 15;
    const int quad = (tid & 63) >> 4;
    const int wrow = (tid >> 6) >> 1, wcol = (tid >> 6) & 1;

    f32x4 acc[4][4] = {};

    for (int k0 = 0; k0 < K; k0 += 32) {
        const float* Au = A; const float* Bu = B; int ku = k0;
        if (DUAL && k0 >= Ksplit) { Au = A2; Bu = B2; ku = k0 - Ksplit; }

        // ---- stage A tile (128 m x 32 k) ----
        if (!TRANS_A) {
#pragma unroll
            for (int p = 0; p < 4; ++p) {
                int idx = tid + p * 256;
                int row = idx >> 3, c4 = idx & 7;
                float4 v = *(const float4*)(Au + (long)(m0 + row) * lda + ku + c4 * 4);
                if (AFFINE) {
                    int k = ku + c4 * 4;
                    v.x = v.x * scale[k] + shift[k];
                    v.y = v.y * scale[k + 1] + shift[k + 1];
                    v.z = v.z * scale[k + 2] + shift[k + 2];
                    v.w = v.w * scale[k + 3] + shift[k + 3];
                }
                *(short4*)&As[row * 40 + c4 * 4] =
                    make_short4(f2bf(v.x), f2bf(v.y), f2bf(v.z), f2bf(v.w));
            }
        } else {
            int c4 = tid & 31, g = tid >> 5;        // 4 m-cols, 4 k-rows per thread
            const float* src = Au + (long)(ku + g * 4) * lda + m0 + c4 * 4;
            float4 r0 = *(const float4*)(src);
            float4 r1 = *(const float4*)(src + lda);
            float4 r2 = *(const float4*)(src + 2 * lda);
            float4 r3 = *(const float4*)(src + 3 * lda);
            short* d = &As[(c4 * 4) * 40 + g * 4];
            *(short4*)(d + 0 * 40) = make_short4(f2bf(r0.x), f2bf(r1.x), f2bf(r2.x), f2bf(r3.x));
            *(short4*)(d + 1 * 40) = make_short4(f2bf(r0.y), f2bf(r1.y), f2bf(r2.y), f2bf(r3.y));
            *(short4*)(d + 2 * 40) = make_short4(f2bf(r0.z), f2bf(r1.z), f2bf(r2.z), f2bf(r3.z));
            *(short4*)(d + 3 * 40) = make_short4(f2bf(r0.w), f2bf(r1.w), f2bf(r2.w), f2bf(r3.w));
        }
        // ---- stage B tile (32 k x 128 n), transposed to Bs[n][k] ----
        {
            int c4 = tid & 31, g = tid >> 5;
            const float* src = Bu + (long)(ku + g * 4) * ldb + n0 + c4 * 4;
            float4 r0 = *(const float4*)(src);
            float4 r1 = *(const float4*)(src + ldb);
            float4 r2 = *(const float4*)(src + 2 * ldb);
            float4 r3 = *(const float4*)(src + 3 * ldb);
            short* d = &Bs[(c4 * 4) * 40 + g * 4];
            *(short4*)(d + 0 * 40) = make_short4(f2bf(r0.x), f2bf(r1.x), f2bf(r2.x), f2bf(r3.x));
            *(short4*)(d + 1 * 40) = make_short4(f2bf(r0.y), f2bf(r1.y), f2bf(r2.y), f2bf(r3.y));
            *(short4*)(d + 2 * 40) = make_short4(f2bf(r0.z), f2bf(r1.z), f2bf(r2.z), f2bf(r3.z));
            *(short4*)(d + 3 * 40) = make_short4(f2bf(r0.w), f2bf(r1.w), f2bf(r2.w), f2bf(r3.w));
        }
        __syncthreads();

        s16x8 af[4], bf[4];
#pragma unroll
        for (int t = 0; t < 4; ++t) {
            af[t] = *(const s16x8*)&As[(wrow * 64 + t * 16 + lane16) * 40 + quad * 8];
            bf[t] = *(const s16x8*)&Bs[(wcol * 64 + t * 16 + lane16) * 40 + quad * 8];
        }
#pragma unroll
        for (int i = 0; i < 4; ++i)
#pragma unroll
            for (int j = 0; j < 4; ++j)
                acc[i][j] = __builtin_amdgcn_mfma_f32_16x16x32_bf16(af[i], bf[j], acc[i][j], 0, 0, 0);
        __syncthreads();
    }

    // ---- epilogue: D[row=quad*4+r][col=lane16] per 16x16 tile ----
#pragma unroll
    for (int i = 0; i < 4; ++i) {
        int gm = m0 + wrow * 64 + i * 16 + quad * 4;
#pragma unroll
        for (int j = 0; j < 4; ++j) {
            int gn = n0 + wcol * 64 + j * 16 + lane16;
            float bv = bias ? bias[gn] : 0.f;
#pragma unroll
            for (int r = 0; r < 4; ++r) {
                float val = acc[i][j][r] + bv;
                if (RELU) val = fmaxf(val, 0.f);
                C[(long)(gm + r) * ldc + gn] = val;
            }
        }
    }
}

// ---------------------------------------------------------------------------
// TransformerConv attention: one wave per dst node, online softmax over its
// incoming edges. h[dst] = relu(agg + skip). qkvs layout: [node][q|k|v|skip].
// ---------------------------------------------------------------------------
__global__ __launch_bounds__(256) void attn_kernel(const float* __restrict__ qkvs,
                                                   const int* __restrict__ ei,
                                                   const float* __restrict__ eattr,
                                                   const float* __restrict__ We,
                                                   const int* __restrict__ rp_dst,
                                                   const int* __restrict__ deg_dst,
                                                   const int* __restrict__ eid_dst,
                                                   float* __restrict__ h) {
    __shared__ float sWe[EDIM_ * 128];
    for (int i = threadIdx.x; i < EDIM_ * 128; i += 256) sWe[i] = We[i];
    __syncthreads();
    int wave = threadIdx.x >> 6;
    int lane = threadIdx.x & 63;
    int node = blockIdx.x * 4 + wave;
    int f0 = lane * 2;
    const float* base = qkvs + (long)node * 512;
    float q0 = base[f0], q1 = base[f0 + 1];
    int start = rp_dst[node], cnt = deg_dst[node];
    float m = -INFINITY, l = 0.f, a0 = 0.f, a1 = 0.f;
    const float inv_sqrt_h = 0.08838834764831845f;  // 1/sqrt(128)
    for (int t = 0; t < cnt; ++t) {
        int e = eid_dst[start + t];
        int src = ei[e];
        const float* kb = qkvs + (long)src * 512 + 128;
        const float* vb = qkvs + (long)src * 512 + 256;
        float e0 = 0.f, e1 = 0.f;
#pragma unroll
        for (int d = 0; d < EDIM_; ++d) {
            float ea = eattr[e * EDIM_ + d];
            e0 += ea * sWe[d * 128 + f0];
            e1 += ea * sWe[d * 128 + f0 + 1];
        }
        float kj0 = kb[f0] + e0, kj1 = kb[f0 + 1] + e1;
        float p = q0 * kj0 + q1 * kj1;
#pragma unroll
        for (int off = 32; off; off >>= 1) p += __shfl_xor(p, off);
        float logit = p * inv_sqrt_h;
        float v0 = vb[f0] + e0, v1 = vb[f0 + 1] + e1;
        float mn = fmaxf(m, logit);
        float sc = expf(m - mn);      // first iter: exp(-inf)=0
        float w = expf(logit - mn);
        l = l * sc + w;
        a0 = a0 * sc + w * v0;
        a1 = a1 * sc + w * v1;
        m = mn;
    }
    float inv = (l > 0.f) ? 1.f / l : 0.f;
    float o0 = fmaxf(a0 * inv + base[384 + f0], 0.f);
    float o1 = fmaxf(a1 * inv + base[384 + f0 + 1], 0.f);
    h[(long)node * 128 + f0]     = o0;
    h[(long)node * 128 + f0 + 1] = o1;
}

// ---------------------------------------------------------------------------
// Row-wise softmax over NC columns, wave per row
// ---------------------------------------------------------------------------
template <int NC>
__global__ __launch_bounds__(256) void softmax_kernel(float* __restrict__ s) {
    int wave = threadIdx.x >> 6;
    int lane = threadIdx.x & 63;
    int row = blockIdx.x * 4 + wave;
    float* p = s + (long)row * NC;
    constexpr int PER = NC / 64;
    float v[PER];
    float mx = -INFINITY;
#pragma unroll
    for (int j = 0; j < PER; ++j) { v[j] = p[lane + j * 64]; mx = fmaxf(mx, v[j]); }
#pragma unroll
    for (int off = 32; off; off >>= 1) mx = fmaxf(mx, __shfl_xor(mx, off));
    float sm = 0.f;
#pragma unroll
    for (int j = 0; j < PER; ++j) { v[j] = expf(v[j] - mx); sm += v[j]; }
#pragma unroll
    for (int off = 32; off; off >>= 1) sm += __shfl_xor(sm, off);
    float inv = 1.f / sm;
#pragma unroll
    for (int j = 0; j < PER; ++j) p[lane + j * 64] = v[j] * inv;
}

// ---------------------------------------------------------------------------
// Sparse T1 = adj @ s1 via CSR-by-src: T1[n,:] = sum over out-edges s1[dst,:]
// ---------------------------------------------------------------------------
__global__ __launch_bounds__(256) void spmm_t1_kernel(const float* __restrict__ s1,
                                                      const int* __restrict__ ei_dst,  // ei + EDGES
                                                      const int* __restrict__ rp_src,
                                                      const int* __restrict__ deg_src,
                                                      const int* __restrict__ eid_src,
                                                      float* __restrict__ T1) {
    int wave = threadIdx.x >> 6;
    int lane = threadIdx.x & 63;
    int node = blockIdx.x * 4 + wave;
    int start = rp_src[node], cnt = deg_src[node];
    float acc[4] = {0.f, 0.f, 0.f, 0.f};
    for (int t = 0; t < cnt; ++t) {
        int e = eid_src[start + t];
        int dst = ei_dst[e];
        const float* sr = s1 + (long)dst * K1C;
#pragma unroll
        for (int j = 0; j < 4; ++j) acc[j] += sr[lane + j * 64];
    }
    float* out = T1 + (long)node * K1C;
#pragma unroll
    for (int j = 0; j < 4; ++j) out[lane + j * 64] = acc[j];
}

// ---------------------------------------------------------------------------
// Pooled-adj normalization
// ---------------------------------------------------------------------------
template <int KC>
__global__ __launch_bounds__(256) void dinv_kernel(const float* __restrict__ adj,
                                                   float* __restrict__ dinv) {
    int wave = threadIdx.x >> 6;
    int lane = threadIdx.x & 63;
    int row = blockIdx.x * 4 + wave;         // in [0, BGRAPH*KC)
    int b = row / KC, r = row % KC;
    const float* p = adj + (long)b * KC * KC + (long)r * KC;
    float s = 0.f;
    for (int j = lane; j < KC; j += 64)
        if (j != r) s += p[j];
#pragma unroll
    for (int off = 32; off; off >>= 1) s += __shfl_xor(s, off);
    if (lane == 0) dinv[row] = 1.f / (sqrtf(s) + 1e-15f);
}

template <int KC>
__global__ __launch_bounds__(256) void scale_adj_kernel(float* __restrict__ adj,
                                                        const float* __restrict__ dinv) {
    long i = (long)blockIdx.x * 256 + threadIdx.x;
    int c = (int)(i % KC);
    long t = i / KC;
    int r = (int)(t % KC);
    int b = (int)(t / KC);
    float v = adj[i];
    v = (r == c) ? 0.f : v * dinv[b * KC + r] * dinv[b * KC + c];
    adj[i] = v;
}

// ---------------------------------------------------------------------------
// Readout
// ---------------------------------------------------------------------------
__global__ __launch_bounds__(128) void readout_kernel(const float* __restrict__ xd3,
                                                      const float* __restrict__ W_lin1,
                                                      const float* __restrict__ b_lin1,
                                                      const float* __restrict__ W_ro,
                                                      const float* __restrict__ b_ro,
                                                      float* __restrict__ out) {
    int b = blockIdx.x, t = threadIdx.x;
    __shared__ float g[128], g2[128], wred[2];
    const float* X = xd3 + (long)b * K2C * 128;
    float s = 0.f;
    for (int r = 0; r < K2C; ++r) s += X[r * 128 + t];
    g[t] = s * (1.f / (float)K2C);
    __syncthreads();
    float u = b_lin1[t];
    for (int k = 0; k < 128; ++k) u += g[k] * W_lin1[k * 128 + t];
    g2[t] = fmaxf(u, 0.f);
    __syncthreads();
    float p = g2[t] * W_ro[t];
#pragma unroll
    for (int off = 32; off; off >>= 1) p += __shfl_xor(p, off);
    if ((t & 63) == 0) wred[t >> 6] = p;
    __syncthreads();
    if (t == 0) {
        float tot = wred[0] + wred[1] + b_ro[0];
        out[b] = 1.f / (1.f + expf(-tot));
    }
}

// ---------------------------------------------------------------------------
extern "C" void kernel_launch(void* const* d_in, const int* in_sizes, int n_in,
                              void* d_out, int out_size, void* d_ws, size_t ws_size,
                              hipStream_t stream) {
    const float* x      = (const float*)d_in[0];
    const int*   ei     = (const int*)d_in[1];
    const float* eattr  = (const float*)d_in[2];
    const float* gamma  = (const float*)d_in[4];
    const float* beta   = (const float*)d_in[5];
    const float* Wq     = (const float*)d_in[6];
    const float* bq     = (const float*)d_in[7];
    const float* Wk     = (const float*)d_in[8];
    const float* bk     = (const float*)d_in[9];
    const float* Wv     = (const float*)d_in[10];
    const float* bv     = (const float*)d_in[11];
    const float* We     = (const float*)d_in[12];
    const float* Wskip  = (const float*)d_in[13];
    const float* bskip  = (const float*)d_in[14];
    const float* W_mlp1 = (const float*)d_in[15];
    const float* b_mlp1 = (const float*)d_in[16];
    const float* W2_rel = (const float*)d_in[17];
    const float* b2_rel = (const float*)d_in[18];
    const float* W2_root= (const float*)d_in[19];
    const float* W_mlp2 = (const float*)d_in[20];
    const float* b_mlp2 = (const float*)d_in[21];
    const float* W3_rel = (const float*)d_in[22];
    const float* b3_rel = (const float*)d_in[23];
    const float* W3_root= (const float*)d_in[24];
    const float* W_lin1 = (const float*)d_in[25];
    const float* b_lin1 = (const float*)d_in[26];
    const float* W_ro   = (const float*)d_in[27];
    const float* b_ro   = (const float*)d_in[28];
    float* out = (float*)d_out;

    char* w = (char*)d_ws;
    const size_t MB = 1ull << 20;
    // Workspace (lifetime-aliased, peak 110 MB) — same plan as round 2.
    float* qkvs = (float*)(w + 0);          // [NTOT,512] 64MB
    float* s1   = (float*)(w + 0);          // [NTOT,256] 32MB
    float* T1   = (float*)(w + 32 * MB);    // [NTOT,256] 32MB
    float* tgc2 = (float*)(w + 32 * MB);    // [B,256,128] 8MB
    float* xd2  = (float*)(w + 40 * MB);    // [B,256,128] 8MB
    float* s2   = (float*)(w + 48 * MB);    // [B,256,128] 8MB
    float* t2   = (float*)(w + 56 * MB);    // [B,256,128] 8MB
    float* adj2 = (float*)(w + 0);          // [B,128,128] 4MB
    float* xp2  = (float*)(w + 4 * MB);     // [B,128,128] 4MB
    float* t3   = (float*)(w + 8 * MB);     // [B,128,128] 4MB
    float* xd3  = (float*)(w + 12 * MB);    // [B,128,128] 4MB
    float* h    = (float*)(w + 64 * MB);    // [NTOT,128] 16MB
    float* adj1 = (float*)(w + 80 * MB);    // [B,256,256] 16MB
    float* xp1  = (float*)(w + 96 * MB);    // [B,256,128] 8MB
    char* misc  = w + 104 * MB;
    float* W4     = (float*)(misc + 0x00000);   // 256KB
    float* bias4  = (float*)(misc + 0x40000);
    float* colsum = (float*)(misc + 0x41000);
    float* colsq  = (float*)(misc + 0x41200);
    float* scale  = (float*)(misc + 0x41400);
    float* shift  = (float*)(misc + 0x41600);
    float* dinv1  = (float*)(misc + 0x42000);
    float* dinv2  = (float*)(misc + 0x52000);
    int* deg_src  = (int*)(misc + 0x60000);
    int* deg_dst  = (int*)(misc + 0x80000);
    int* rp_src   = (int*)(misc + 0xA0000);
    int* rp_dst   = (int*)(misc + 0xC0000);
    int* cur_src  = (int*)(misc + 0xE0000);
    int* cur_dst  = (int*)(misc + 0x100000);
    int* eid_src  = (int*)(misc + 0x120000);
    int* eid_dst  = (int*)(misc + 0x320000);

    hipMemsetAsync(colsum, 0, 1024, stream);
    hipMemsetAsync(deg_src, 0, 2 * NTOT * sizeof(int), stream);

    // 1. BatchNorm affine params
    bn_stats_kernel<<<64, 256, 0, stream>>>(x, colsum, colsq);
    bn_finalize_kernel<<<1, 128, 0, stream>>>(colsum, colsq, gamma, beta, scale, shift);

    // 2. Pack fused qkvs weights
    pack_w4_kernel<<<256, 256, 0, stream>>>(Wq, Wk, Wv, Wskip, bq, bk, bv, bskip, W4, bias4);

    // 3. CSR by src and dst
    hist_kernel<<<EDGES / 256, 256, 0, stream>>>(ei, deg_src, deg_dst);
    scan_kernel<<<1, 1024, 0, stream>>>(deg_src, rp_src, cur_src);
    scan_kernel<<<1, 1024, 0, stream>>>(deg_dst, rp_dst, cur_dst);
    scatter_kernel<<<EDGES / 256, 256, 0, stream>>>(ei, cur_src, cur_dst, eid_src, eid_dst);

    // 4. qkvs = BN(x) @ [Wq|Wk|Wv|Wskip] + biases (BN fused into A staging)
    mgemm<false, true, false, false><<<dim3(4, 256, 1), 256, 0, stream>>>(
        x, W4, nullptr, nullptr, 0, bias4, qkvs, scale, shift,
        NTOT, 512, 128, 128, 512, 512, 0, 0, 0);

    // 5. Edge-softmax attention -> h = relu(agg + skip)
    attn_kernel<<<NTOT / 4, 256, 0, stream>>>(qkvs, ei, eattr, We, rp_dst, deg_dst, eid_dst, h);

    // 6. s1 = softmax(h @ W_mlp1 + b_mlp1)
    mgemm<false, false, false, false><<<dim3(2, 256, 1), 256, 0, stream>>>(
        h, W_mlp1, nullptr, nullptr, 0, b_mlp1, s1, nullptr, nullptr,
        NTOT, K1C, 128, 128, K1C, K1C, 0, 0, 0);
    softmax_kernel<K1C><<<NTOT / 4, 256, 0, stream>>>(s1);

    // 7. T1 = adj @ s1 (sparse)
    spmm_t1_kernel<<<NTOT / 4, 256, 0, stream>>>(s1, ei + EDGES, rp_src, deg_src, eid_src, T1);

    // 8. adj1 = s1^T T1 ; xp1 = s1^T h (batched per graph)
    mgemm<true, false, false, false><<<dim3(2, 2, BGRAPH), 256, 0, stream>>>(
        s1, T1, nullptr, nullptr, 0, nullptr, adj1, nullptr, nullptr,
        K1C, K1C, NNODE, K1C, K1C, K1C,
        (long)NNODE * K1C, (long)NNODE * K1C, (long)K1C * K1C);
    mgemm<true, false, false, false><<<dim3(1, 2, BGRAPH), 256, 0, stream>>>(
        s1, h, nullptr, nullptr, 0, nullptr, xp1, nullptr, nullptr,
        K1C, 128, NNODE, K1C, 128, 128,
        (long)NNODE * K1C, (long)NNODE * 128, (long)K1C * 128);

    // 9. Normalize adj1
    dinv_kernel<K1C><<<(BGRAPH * K1C) / 4, 256, 0, stream>>>(adj1, dinv1);
    scale_adj_kernel<K1C><<<(BGRAPH * K1C * K1C) / 256, 256, 0, stream>>>(adj1, dinv1);

    // 10. GraphConv2: tgc2 = adj1 @ xp1 ; xd2 = relu([tgc2|xp1] @ [W2_rel;W2_root] + b)
    mgemm<false, false, false, false><<<dim3(1, 2, BGRAPH), 256, 0, stream>>>(
        adj1, xp1, nullptr, nullptr, 0, nullptr, tgc2, nullptr, nullptr,
        K1C, 128, K1C, K1C, 128, 128,
        (long)K1C * K1C, (long)K1C * 128, (long)K1C * 128);
    mgemm<false, false, true, true><<<dim3(1, 128, 1), 256, 0, stream>>>(
        tgc2, W2_rel, xp1, W2_root, 128, b2_rel, xd2, nullptr, nullptr,
        BGRAPH * K1C, 128, 256, 128, 128, 128, 0, 0, 0);

    // 11. s2 = softmax(xd2 @ W_mlp2 + b_mlp2)
    mgemm<false, false, false, false><<<dim3(1, 128, 1), 256, 0, stream>>>(
        xd2, W_mlp2, nullptr, nullptr, 0, b_mlp2, s2, nullptr, nullptr,
        BGRAPH * K1C, K2C, 128, 128, K2C, K2C, 0, 0, 0);
    softmax_kernel<K2C><<<(BGRAPH * K1C) / 4, 256, 0, stream>>>(s2);

    // 12. Pool2: t2 = adj1 @ s2 ; adj2 = s2^T t2 ; xp2 = s2^T xd2
    mgemm<false, false, false, false><<<dim3(1, 2, BGRAPH), 256, 0, stream>>>(
        adj1, s2, nullptr, nullptr, 0, nullptr, t2, nullptr, nullptr,
        K1C, K2C, K1C, K1C, K2C, K2C,
        (long)K1C * K1C, (long)K1C * K2C, (long)K1C * K2C);
    mgemm<true, false, false, false><<<dim3(1, 1, BGRAPH), 256, 0, stream>>>(
        s2, t2, nullptr, nullptr, 0, nullptr, adj2, nullptr, nullptr,
        K2C, K2C, K1C, K2C, K2C, K2C,
        (long)K1C * K2C, (long)K1C * K2C, (long)K2C * K2C);
    mgemm<true, false, false, false><<<dim3(1, 1, BGRAPH), 256, 0, stream>>>(
        s2, xd2, nullptr, nullptr, 0, nullptr, xp2, nullptr, nullptr,
        K2C, 128, K1C, K2C, 128, 128,
        (long)K1C * K2C, (long)K1C * 128, (long)K2C * 128);

    // 13. Normalize adj2
    dinv_kernel<K2C><<<(BGRAPH * K2C) / 4, 256, 0, stream>>>(adj2, dinv2);
    scale_adj_kernel<K2C><<<(BGRAPH * K2C * K2C) / 256, 256, 0, stream>>>(adj2, dinv2);

    // 14. GraphConv3: t3 = adj2 @ xp2 ; xd3 = [t3|xp2] @ [W3_rel;W3_root] + b (no relu)
    mgemm<false, false, false, false><<<dim3(1, 1, BGRAPH), 256, 0, stream>>>(
        adj2, xp2, nullptr, nullptr, 0, nullptr, t3, nullptr, nullptr,
        K2C, 128, K2C, K2C, 128, 128,
        (long)K2C * K2C, (long)K2C * 128, (long)K2C * 128);
    mgemm<false, false, false, true><<<dim3(1, 64, 1), 256, 0, stream>>>(
        t3, W3_rel, xp2, W3_root, 128, b3_rel, xd3, nullptr, nullptr,
        BGRAPH * K2C, 128, 256, 128, 128, 128, 0, 0, 0);

    // 15. Readout -> sigmoid [B]
    readout_kernel<<<BGRAPH, 128, 0, stream>>>(xd3, W_lin1, b_lin1, W_ro, b_ro, out);

    (void)in_sizes; (void)n_in; (void)out_size; (void)ws_size;
}